// Round 4
// baseline (235.954 us; speedup 1.0000x reference)
//
#include <hip/hip_runtime.h>

#define BATCH 8
#define SEQ   2048
#define EMB   1024
#define HD    64
#define HEADS 16
#define LOG2E 1.4426950408889634f

typedef _Float16 half8 __attribute__((ext_vector_type(8)));
typedef _Float16 half4 __attribute__((ext_vector_type(4)));
typedef float    f32x4 __attribute__((ext_vector_type(4)));

__device__ __forceinline__ float fexp2(float x) {
#if __has_builtin(__builtin_amdgcn_exp2f)
    return __builtin_amdgcn_exp2f(x);
#else
    return exp2f(x);
#endif
}

// load 8 consecutive f32, convert to 8 fp16
__device__ __forceinline__ half8 cvt8(const float* __restrict__ src) {
    float4 f0 = *(const float4*)src;
    float4 f1 = *(const float4*)(src + 4);
    half8 h;
    h[0] = (_Float16)f0.x; h[1] = (_Float16)f0.y; h[2] = (_Float16)f0.z; h[3] = (_Float16)f0.w;
    h[4] = (_Float16)f1.x; h[5] = (_Float16)f1.y; h[6] = (_Float16)f1.z; h[7] = (_Float16)f1.w;
    return h;
}

// ---------------- W -> fp16 (Wq pre-scaled by log2e so scores are in log2 domain)
__global__ __launch_bounds__(256) void wcvt_kernel(
    const float* __restrict__ Wq, const float* __restrict__ Wk,
    const float* __restrict__ Wv, _Float16* __restrict__ Wh)
{
    const int m = blockIdx.y;
    const float* src = (m == 0) ? Wq : (m == 1) ? Wk : Wv;
    const float scale = (m == 0) ? LOG2E : 1.0f;
    const int idx = (blockIdx.x * 256 + threadIdx.x) * 8;   // < 65536
    float4 f0 = *(const float4*)(src + idx);
    float4 f1 = *(const float4*)(src + idx + 4);
    half8 h;
    h[0] = (_Float16)(f0.x * scale); h[1] = (_Float16)(f0.y * scale);
    h[2] = (_Float16)(f0.z * scale); h[3] = (_Float16)(f0.w * scale);
    h[4] = (_Float16)(f1.x * scale); h[5] = (_Float16)(f1.y * scale);
    h[6] = (_Float16)(f1.z * scale); h[7] = (_Float16)(f1.w * scale);
    *(half8*)(Wh + (size_t)m * 65536 + idx) = h;
}

// ---------------- QKV projection: direct-global fragments, no LDS, no barriers
// grid (256, 3) x 256 thr. Wave = 16 rows x 64 out-cols of matrix m.
__global__ __launch_bounds__(256) void qkv_kernel(
    const float* __restrict__ x, const _Float16* __restrict__ Wh,
    _Float16* __restrict__ qh, _Float16* __restrict__ kh, _Float16* __restrict__ vpt)
{
    const int t = threadIdx.x, lane = t & 63, wave = t >> 6;
    const int l15 = lane & 15, quad = lane >> 4;
    const int m = blockIdx.y;
    const int row0 = blockIdx.x * 64 + wave * 16;           // [0, 16384)
    const _Float16* __restrict__ W = Wh + (size_t)m * 65536;
    const float* __restrict__ xrow = x + (size_t)(row0 + l15) * EMB;

    f32x4 acc[4] = {};
    for (int k0 = 0; k0 < EMB; k0 += 64) {
        half8 a0 = cvt8(xrow + k0 + quad * 8);
        half8 a1 = cvt8(xrow + k0 + 32 + quad * 8);
        #pragma unroll
        for (int ct = 0; ct < 4; ++ct) {
            half8 b0 = *(const half8*)(W + (size_t)(ct * 16 + l15) * EMB + k0 + quad * 8);
            half8 b1 = *(const half8*)(W + (size_t)(ct * 16 + l15) * EMB + k0 + 32 + quad * 8);
            acc[ct] = __builtin_amdgcn_mfma_f32_16x16x32_f16(a0, b0, acc[ct], 0, 0, 0);
            acc[ct] = __builtin_amdgcn_mfma_f32_16x16x32_f16(a1, b1, acc[ct], 0, 0, 0);
        }
    }
    if (m < 2) {
        _Float16* __restrict__ dst = (m == 0) ? qh : kh;
        #pragma unroll
        for (int ct = 0; ct < 4; ++ct)
            #pragma unroll
            for (int r = 0; r < 4; ++r)
                dst[(size_t)(row0 + quad * 4 + r) * HD + ct * 16 + l15] = (_Float16)acc[ct][r];
    } else {
        // v transposed: vpt[b][d][s]; lane's 4 rows are 4 consecutive s -> 8B store
        const int rg = row0 + quad * 4;
        const int b = rg >> 11, s = rg & 2047;
        #pragma unroll
        for (int ct = 0; ct < 4; ++ct) {
            half4 h;
            h[0] = (_Float16)acc[ct][0]; h[1] = (_Float16)acc[ct][1];
            h[2] = (_Float16)acc[ct][2]; h[3] = (_Float16)acc[ct][3];
            *(half4*)(vpt + ((size_t)b * HD + ct * 16 + l15) * SEQ + s) = h;
        }
    }
}

// ---------------- Column-softmax denominators
// l_inv[b,c] = 1 / sum_i exp2(q~[b,i,:] . k[b,c,:]).  grid (128, 8) x 256 (4 waves).
// Block owns 16 key cols; wave w sweeps query rows [w*512, (w+1)*512).
__global__ __launch_bounds__(256) void stats_kernel(
    const _Float16* __restrict__ qh, const _Float16* __restrict__ kh,
    float* __restrict__ l_inv)
{
    __shared__ float red[4][16];
    const int t = threadIdx.x, lane = t & 63, wave = t >> 6;
    const int l15 = lane & 15, quad = lane >> 4;
    const int b = blockIdx.y, c0 = blockIdx.x * 16;

    const _Float16* __restrict__ kp = kh + ((size_t)b * SEQ + c0 + l15) * HD + quad * 8;
    half8 bf0 = *(const half8*)(kp);
    half8 bf1 = *(const half8*)(kp + 32);

    const _Float16* __restrict__ qbase =
        qh + ((size_t)b * SEQ + wave * 512 + l15) * HD + quad * 8;
    float csum = 0.f;
    #pragma unroll 4
    for (int r = 0; r < 512; r += 16) {
        const _Float16* qp = qbase + (size_t)r * HD;
        half8 a0 = *(const half8*)(qp);
        half8 a1 = *(const half8*)(qp + 32);
        f32x4 s = {};
        s = __builtin_amdgcn_mfma_f32_16x16x32_f16(a0, bf0, s, 0, 0, 0);
        s = __builtin_amdgcn_mfma_f32_16x16x32_f16(a1, bf1, s, 0, 0, 0);
        csum += fexp2(s[0]) + fexp2(s[1]) + fexp2(s[2]) + fexp2(s[3]);
    }
    csum += __shfl_xor(csum, 16);
    csum += __shfl_xor(csum, 32);
    if (lane < 16) red[wave][l15] = csum;
    __syncthreads();
    if (t < 16)
        l_inv[(size_t)b * SEQ + c0 + t] =
            1.0f / (red[0][t] + red[1][t] + red[2][t] + red[3][t]);
}

// ---------------- out = P~ @ v, P~ = exp2(s~) * l_inv[key], fp16 MFMA both stages
// grid (64, 8) x 256 (4 waves). Block: 32 q-rows; wave w sweeps keys [w*512,(w+1)*512).
// Barrier-free main loop: P round-trips wave-private LDS (lgkmcnt only).
__global__ __launch_bounds__(256) void out_kernel(
    const _Float16* __restrict__ qh, const _Float16* __restrict__ kh,
    const _Float16* __restrict__ vpt, const float* __restrict__ l_inv,
    float* __restrict__ out)
{
    __shared__ _Float16 ps[4][32][72];      // wave-private P~ tiles
    __shared__ float red[2][32][68];        // cross-wave O reduction + epilogue tile
    const int t = threadIdx.x, lane = t & 63, wave = t >> 6;
    const int l15 = lane & 15, quad = lane >> 4;
    const int b = blockIdx.y, r0 = blockIdx.x * 32;

    half8 aq[2][2];
    #pragma unroll
    for (int rt = 0; rt < 2; ++rt)
        #pragma unroll
        for (int kc = 0; kc < 2; ++kc)
            aq[rt][kc] = *(const half8*)(qh + ((size_t)b * SEQ + r0 + rt * 16 + l15) * HD
                                         + kc * 32 + quad * 8);

    f32x4 oacc[2][4] = {};
    const int kq0 = wave * 512;
    for (int it = 0; it < 8; ++it) {
        const int c0 = kq0 + it * 64;
        float li[4];
        half8 kb[4][2];
        #pragma unroll
        for (int ct = 0; ct < 4; ++ct) {
            li[ct] = l_inv[(size_t)b * SEQ + c0 + ct * 16 + l15];
            const _Float16* kp = kh + ((size_t)b * SEQ + c0 + ct * 16 + l15) * HD + quad * 8;
            kb[ct][0] = *(const half8*)(kp);
            kb[ct][1] = *(const half8*)(kp + 32);
        }
        f32x4 s[2][4] = {};
        #pragma unroll
        for (int kc = 0; kc < 2; ++kc)
            #pragma unroll
            for (int rt = 0; rt < 2; ++rt)
                #pragma unroll
                for (int ct = 0; ct < 4; ++ct)
                    s[rt][ct] = __builtin_amdgcn_mfma_f32_16x16x32_f16(
                        aq[rt][kc], kb[ct][kc], s[rt][ct], 0, 0, 0);
        #pragma unroll
        for (int rt = 0; rt < 2; ++rt)
            #pragma unroll
            for (int ct = 0; ct < 4; ++ct)
                #pragma unroll
                for (int r = 0; r < 4; ++r)
                    ps[wave][rt * 16 + quad * 4 + r][ct * 16 + l15] =
                        (_Float16)(fexp2(s[rt][ct][r]) * li[ct]);
        half8 pa[2][2], vb[4][2];
        #pragma unroll
        for (int rt = 0; rt < 2; ++rt)
            #pragma unroll
            for (int kc = 0; kc < 2; ++kc)
                pa[rt][kc] = *(half8*)&ps[wave][rt * 16 + l15][kc * 32 + quad * 8];
        #pragma unroll
        for (int n = 0; n < 4; ++n) {
            const _Float16* vp = vpt + ((size_t)b * HD + n * 16 + l15) * SEQ + c0 + quad * 8;
            vb[n][0] = *(const half8*)(vp);
            vb[n][1] = *(const half8*)(vp + 32);
        }
        #pragma unroll
        for (int kc = 0; kc < 2; ++kc)
            #pragma unroll
            for (int rt = 0; rt < 2; ++rt)
                #pragma unroll
                for (int n = 0; n < 4; ++n)
                    oacc[rt][n] = __builtin_amdgcn_mfma_f32_16x16x32_f16(
                        pa[rt][kc], vb[n][kc], oacc[rt][n], 0, 0, 0);
    }

    // cross-wave reduction of the 4 key-range partials
    #define DUMP(slot)                                                          \
        { _Pragma("unroll") for (int rt = 0; rt < 2; ++rt)                      \
          _Pragma("unroll") for (int n = 0; n < 4; ++n)                         \
          _Pragma("unroll") for (int r = 0; r < 4; ++r)                         \
              red[slot][rt * 16 + quad * 4 + r][n * 16 + l15] = oacc[rt][n][r]; }
    #define ADDIN(slot)                                                         \
        { _Pragma("unroll") for (int rt = 0; rt < 2; ++rt)                      \
          _Pragma("unroll") for (int n = 0; n < 4; ++n)                         \
          _Pragma("unroll") for (int r = 0; r < 4; ++r)                         \
              oacc[rt][n][r] += red[slot][rt * 16 + quad * 4 + r][n * 16 + l15]; }
    if (wave == 1) DUMP(0);
    if (wave == 2) DUMP(1);
    __syncthreads();
    if (wave == 0) ADDIN(0);
    if (wave == 3) ADDIN(1);
    __syncthreads();
    if (wave == 3) DUMP(0);
    __syncthreads();
    if (wave == 0) { ADDIN(0); DUMP(1); }
    __syncthreads();

    // epilogue: 32x64 tile from red[1], written x16 heads, coalesced float4
    const int row = t >> 3, seg = t & 7;
    float4 u0 = *(float4*)&red[1][row][seg * 8];
    float4 u1 = *(float4*)&red[1][row][seg * 8 + 4];
    size_t base = ((size_t)b * SEQ + r0 + row) * (HD * HEADS);
    #pragma unroll
    for (int h = 0; h < HEADS; ++h) {
        *(float4*)&out[base + h * HD + seg * 8]     = u0;
        *(float4*)&out[base + h * HD + seg * 8 + 4] = u1;
    }
}

extern "C" void kernel_launch(void* const* d_in, const int* in_sizes, int n_in,
                              void* d_out, int out_size, void* d_ws, size_t ws_size,
                              hipStream_t stream)
{
    const float* x  = (const float*)d_in[0];
    const float* Wq = (const float*)d_in[1];
    const float* Wk = (const float*)d_in[2];
    const float* Wv = (const float*)d_in[3];
    float* out = (float*)d_out;

    const size_t N = (size_t)BATCH * SEQ * HD;   // 1,048,576
    _Float16* qh  = (_Float16*)d_ws;
    _Float16* kh  = qh + N;
    _Float16* vpt = kh + N;
    _Float16* Wh  = vpt + N;                     // 3*64*1024 = 196608 halves
    float* l_inv  = (float*)(Wh + 196608);       // 16384 floats; total ~6.75 MB

    wcvt_kernel <<<dim3(32, 3),  256, 0, stream>>>(Wq, Wk, Wv, Wh);
    qkv_kernel  <<<dim3(256, 3), 256, 0, stream>>>(x, Wh, qh, kh, vpt);
    stats_kernel<<<dim3(128, 8), 256, 0, stream>>>(qh, kh, l_inv);
    out_kernel  <<<dim3(64, 8),  256, 0, stream>>>(qh, kh, vpt, l_inv, out);
}